// Round 1
// baseline (317.784 us; speedup 1.0000x reference)
//
#include <hip/hip_runtime.h>
#include <stdint.h>

typedef __attribute__((ext_vector_type(8))) short bf16x8;
typedef __attribute__((ext_vector_type(4))) float f32x4;
typedef unsigned short u16;
typedef unsigned int   u32;

#define S_LEN 2048
#define NH    16
#define NKV   4
#define DH    128
#define DM    2048
#define QKV_N 3072
#define MROWS 4096   // B*S

__device__ __forceinline__ u16 f2bf(float x) {
  u32 u = __float_as_uint(x);
  return (u16)((u + 0x7fffu + ((u >> 16) & 1u)) >> 16);   // RNE
}
__device__ __forceinline__ float bf2f(u16 h) {
  return __uint_as_float(((u32)h) << 16);
}
__device__ __forceinline__ u32 packbf(float lo, float hi) {
  return (u32)f2bf(lo) | ((u32)f2bf(hi) << 16);
}
__device__ __forceinline__ void gload_lds16(const void* g, void* l) {
  __builtin_amdgcn_global_load_lds((const __attribute__((address_space(1))) void*)g,
                                   (__attribute__((address_space(3))) void*)l, 16, 0, 0);
}

// ---------------- f32 -> bf16 convert (vectorized, G13) ----------------
__global__ void __launch_bounds__(256) convert_x_kernel(const float* __restrict__ x,
                                                        u16* __restrict__ o) {
  int idx = (blockIdx.x * 256 + threadIdx.x) * 8;
  float4 a = *(const float4*)(x + idx);
  float4 b = *(const float4*)(x + idx + 4);
  union { u16 s[8]; uint4 v; } t;
  t.s[0] = f2bf(a.x); t.s[1] = f2bf(a.y); t.s[2] = f2bf(a.z); t.s[3] = f2bf(a.w);
  t.s[4] = f2bf(b.x); t.s[5] = f2bf(b.y); t.s[6] = f2bf(b.z); t.s[7] = f2bf(b.w);
  *(uint4*)(o + idx) = t.v;
}

// ------------- W [2048][N] f32  ->  Wt [N][2048] bf16 (LDS tiled) -------------
__global__ void __launch_bounds__(256) transpose_w_kernel(const float* __restrict__ src,
                                                          u16* __restrict__ dst, int N) {
  __shared__ float t[64][65];
  const int bx = blockIdx.x, by = blockIdx.y, tid = threadIdx.x;
#pragma unroll
  for (int rep = 0; rep < 16; ++rep) {
    int lin = rep * 256 + tid;
    int i = lin >> 6, jj = lin & 63;                 // i = k-local, jj = n-local
    t[i][jj] = src[(size_t)(bx * 64 + i) * N + by * 64 + jj];
  }
  __syncthreads();
#pragma unroll
  for (int rep = 0; rep < 16; ++rep) {
    int lin = rep * 256 + tid;
    int nr = lin >> 6, kc = lin & 63;
    dst[(size_t)(by * 64 + nr) * DM + bx * 64 + kc] = f2bf(t[kc][nr]);
  }
}

// ------------- RoPE tables: ctab/stab[s*64 + i] -------------
__global__ void __launch_bounds__(256) rope_tables_kernel(float* __restrict__ ct,
                                                          float* __restrict__ st_) {
  int idx = blockIdx.x * 256 + threadIdx.x;          // 2048*64
  int s = idx >> 6, i = idx & 63;
  const float L2_10000 = 13.287712379549449f;
  float freq = exp2f(-(float)i * (1.0f / 64.0f) * L2_10000);
  float ang = (float)s * freq;
  ct[idx] = cosf(ang);
  st_[idx] = sinf(ang);
}

// ------------- GEMM: C[M][N] = A[M][K](bf16) * Bt[N][K](bf16)^T  (m97 structure) -------------
template <int OUTF32>
__global__ void __launch_bounds__(256) gemm_bt(const u16* __restrict__ A,
                                               const u16* __restrict__ Bt,
                                               void* __restrict__ C,
                                               int M, int N, int K) {
  __shared__ __align__(16) u16 As[128 * 32];
  __shared__ __align__(16) u16 Bs[128 * 32];
  const int tid = threadIdx.x;
  const int w = tid >> 6, l = tid & 63;
  const int g = l >> 4, q15 = l & 15;
  const int row0 = blockIdx.y * 128, col0 = blockIdx.x * 128;
  const int wm = (w >> 1) * 64, wn = (w & 1) * 64;
  const f32x4 fz = {0.f, 0.f, 0.f, 0.f};
  f32x4 acc[4][4];
#pragma unroll
  for (int m = 0; m < 4; ++m)
#pragma unroll
    for (int n = 0; n < 4; ++n) acc[m][n] = fz;

  for (int kt = 0; kt < K; kt += 32) {
#pragma unroll
    for (int c = 0; c < 2; ++c) {
      int P = (w * 2 + c) * 1024;
      int Pl = P + l * 16;
      int arow = Pl >> 6, acolb = Pl & 63;          // 64B per 32-elem row
      gload_lds16((const char*)A + ((size_t)(row0 + arow) * K + kt) * 2 + acolb,
                  (char*)As + P);
      gload_lds16((const char*)Bt + ((size_t)(col0 + arow) * K + kt) * 2 + acolb,
                  (char*)Bs + P);
    }
    __syncthreads();
    bf16x8 af[4], bfv[4];
#pragma unroll
    for (int m = 0; m < 4; ++m)
      af[m] = *(const bf16x8*)((const char*)As + (wm + m * 16 + q15) * 64 + g * 16);
#pragma unroll
    for (int n = 0; n < 4; ++n)
      bfv[n] = *(const bf16x8*)((const char*)Bs + (wn + n * 16 + q15) * 64 + g * 16);
#pragma unroll
    for (int m = 0; m < 4; ++m)
#pragma unroll
      for (int n = 0; n < 4; ++n)
        acc[m][n] = __builtin_amdgcn_mfma_f32_16x16x32_bf16(af[m], bfv[n], acc[m][n], 0, 0, 0);
    __syncthreads();
  }
#pragma unroll
  for (int m = 0; m < 4; ++m)
#pragma unroll
    for (int n = 0; n < 4; ++n)
#pragma unroll
      for (int r = 0; r < 4; ++r) {
        int rr = row0 + wm + m * 16 + g * 4 + r;    // C/D: row=(l>>4)*4+reg
        int cc = col0 + wn + n * 16 + q15;          //      col=l&15
        float v = acc[m][n][r];
        if (OUTF32) ((float*)C)[(size_t)rr * N + cc] = v;
        else        ((u16*)C)[(size_t)rr * N + cc]  = f2bf(v);
      }
}

// ------------- fused RMSNorm + RoPE; one wave per (row, head-job) -------------
// jobs 0..15 = q heads (pre-scaled by 1/sqrt(DH)), 16..19 = k heads
__global__ void __launch_bounds__(256) norm_rope_kernel(const u16* __restrict__ qkv,
                                                        const float* __restrict__ qw,
                                                        const float* __restrict__ kw,
                                                        const float* __restrict__ ct,
                                                        const float* __restrict__ st_,
                                                        u16* __restrict__ Qo,
                                                        u16* __restrict__ Ko) {
  int wid = blockIdx.x * 4 + (threadIdx.x >> 6);
  int l = threadIdx.x & 63;
  int row = wid / 20;
  int j = wid - row * 20;
  int b = row >> 11, s = row & 2047;
  bool isq = j < 16;
  int h = isq ? j : (j - 16);
  const u16* src = qkv + (size_t)row * QKV_N + (isq ? h * DH : (2048 + h * DH));
  float x1 = bf2f(src[l]), x2 = bf2f(src[l + 64]);
  float ss = x1 * x1 + x2 * x2;
#pragma unroll
  for (int off = 32; off > 0; off >>= 1) ss += __shfl_xor(ss, off);
  float rn = rsqrtf(ss * (1.0f / 128.0f) + 1e-6f);
  const float* wv = isq ? qw : kw;
  float n1 = x1 * rn * wv[l], n2 = x2 * rn * wv[l + 64];
  float cv = ct[s * 64 + l], sv = st_[s * 64 + l];
  float o1 = n1 * cv - n2 * sv;
  float o2 = n2 * cv + n1 * sv;
  float scale = isq ? 0.08838834764831845f : 1.0f;   // 1/sqrt(128) folded into Q
  u16* dst = isq ? (Qo + ((size_t)(b * NH + h) * S_LEN + s) * DH)
                 : (Ko + ((size_t)(b * NKV + h) * S_LEN + s) * DH);
  dst[l]      = f2bf(o1 * scale);
  dst[l + 64] = f2bf(o2 * scale);
}

// ------------- V transpose: qkv[...,2560+h*128+d] -> vt[(b*4+h)*128+d][S] -------------
__global__ void __launch_bounds__(256) vtrans_kernel(const u16* __restrict__ qkv,
                                                     u16* __restrict__ vt) {
  __shared__ u16 t[64][65];
  const int st = blockIdx.x, dt = blockIdx.y, bz = blockIdx.z;  // bz = b*4+h
  const int tid = threadIdx.x;
#pragma unroll
  for (int rep = 0; rep < 16; ++rep) {
    int lin = rep * 256 + tid;
    int i = lin >> 6, jj = lin & 63;                // i = s-local, jj = d-local
    t[i][jj] = qkv[(size_t)((bz >> 2) * S_LEN + st * 64 + i) * QKV_N
                   + 2560 + (bz & 3) * DH + dt * 64 + jj];
  }
  __syncthreads();
#pragma unroll
  for (int rep = 0; rep < 16; ++rep) {
    int lin = rep * 256 + tid;
    int dr = lin >> 6, sc = lin & 63;
    vt[((size_t)bz * DH + dt * 64 + dr) * S_LEN + st * 64 + sc] = t[sc][dr];
  }
}

// ------------- flash attention: 64 q-rows/block, 4 waves (16 q each), KV tile 64 -------------
__global__ void __launch_bounds__(256) attn_kernel(const u16* __restrict__ Qg,
                                                   const u16* __restrict__ Kg,
                                                   const u16* __restrict__ Vt,
                                                   u16* __restrict__ O) {
  __shared__ __align__(16) char smem[32768];
  char* Ks = smem;              // [64 kv][128 d] bf16, rows 256B, XOR-swizzled
  char* Vs = smem + 16384;      // [128 d][64 kv] bf16, rows 128B, XOR-swizzled
  const int tid = threadIdx.x;
  const int w = tid >> 6, l = tid & 63;
  const int g = l >> 4, q15 = l & 15;
  const int qb = blockIdx.x * 64;
  const int bh = blockIdx.y;                  // b*16 + h
  const int b = bh >> 4, h = bh & 15;
  const int kvh = h >> 2;                     // GQA: 4 q-heads per kv-head

  // Q rows in registers: lane holds query row (qb + w*16 + q15), k-chunk g*8 within 32-chunk c
  bf16x8 qreg[4];
  const u16* Qrow = Qg + ((size_t)(b * NH + h) * S_LEN + qb + w * 16 + q15) * DH;
#pragma unroll
  for (int c = 0; c < 4; ++c)
    qreg[c] = *(const bf16x8*)(Qrow + c * 32 + g * 8);

  const char* Kbase = (const char*)(Kg + (size_t)(b * NKV + kvh) * S_LEN * DH);
  const char* Vbase = (const char*)(Vt + (size_t)(b * NKV + kvh) * DH * S_LEN);

  const f32x4 fz = {0.f, 0.f, 0.f, 0.f};
  f32x4 acc[8];
#pragma unroll
  for (int n = 0; n < 8; ++n) acc[n] = fz;
  float mrun = -1e30f, lrun = 0.f;
  const int nkt = blockIdx.x;

  for (int kt = 0; kt <= nkt; ++kt) {
    const char* Kt  = Kbase + (size_t)kt * 64 * 256;   // 64 rows * 256B
    const char* Vtb = Vbase + (size_t)kt * 128;        // kv col offset, bytes
#pragma unroll
    for (int i = 0; i < 4; ++i) {
      int P = i * 4096 + w * 1024;
      int Pl = P + l * 16;
      { // K: dest linear, source pre-swizzled (rule 21)
        int row = Pl >> 8; int cb = (Pl & 255) ^ ((row & 7) << 4);
        gload_lds16(Kt + (size_t)row * 256 + cb, Ks + P);
      }
      { // Vt: rows are 128B (stride S*2 in global)
        int row = Pl >> 7; int cb = (Pl & 127) ^ ((row & 7) << 4);
        gload_lds16(Vtb + (size_t)row * (S_LEN * 2) + cb, Vs + P);
      }
    }
    __syncthreads();

    // QK^T swapped: D = K * Q^T -> S^T[kv][q]; lane: q=l&15, kv=st*16+4g+r
    f32x4 sa[4];
#pragma unroll
    for (int stt = 0; stt < 4; ++stt) sa[stt] = fz;
#pragma unroll
    for (int stt = 0; stt < 4; ++stt) {
      int krow = stt * 16 + q15;
      const char* kr = Ks + krow * 256;
      int sw = (krow & 7) << 4;
#pragma unroll
      for (int c = 0; c < 4; ++c) {
        bf16x8 kf = *(const bf16x8*)(kr + ((c * 64 + g * 16) ^ sw));
        sa[stt] = __builtin_amdgcn_mfma_f32_16x16x32_bf16(kf, qreg[c], sa[stt], 0, 0, 0);
      }
    }

    // online softmax (scale pre-folded into Q)
    const bool domask = (kt == nkt);
    float sv[16];
    float tmax = -1e30f;
#pragma unroll
    for (int stt = 0; stt < 4; ++stt)
#pragma unroll
      for (int r = 0; r < 4; ++r) {
        float v = sa[stt][r];
        if (domask) {
          int kvg = kt * 64 + stt * 16 + g * 4 + r;
          int qg  = qb + w * 16 + q15;
          if (kvg > qg) v = -1e30f;
        }
        sv[stt * 4 + r] = v;
        tmax = fmaxf(tmax, v);
      }
    tmax = fmaxf(tmax, __shfl_xor(tmax, 16));
    tmax = fmaxf(tmax, __shfl_xor(tmax, 32));
    float mnew = fmaxf(mrun, tmax);
    float alpha = __expf(mrun - mnew);
    float tsum = 0.f;
    u32 pk[4][2];
#pragma unroll
    for (int stt = 0; stt < 4; ++stt) {
      float p0 = __expf(sv[stt * 4 + 0] - mnew);
      float p1 = __expf(sv[stt * 4 + 1] - mnew);
      float p2 = __expf(sv[stt * 4 + 2] - mnew);
      float p3 = __expf(sv[stt * 4 + 3] - mnew);
      tsum += p0 + p1 + p2 + p3;
      pk[stt][0] = packbf(p0, p1);
      pk[stt][1] = packbf(p2, p3);
    }
    tsum += __shfl_xor(tsum, 16);
    tsum += __shfl_xor(tsum, 32);
    lrun = lrun * alpha + tsum;
    mrun = mnew;

    // rescale acc rows (row q' = 4g+r needs alpha of lane q')
    float af4[4];
#pragma unroll
    for (int r = 0; r < 4; ++r) af4[r] = __shfl(alpha, g * 4 + r);
#pragma unroll
    for (int n = 0; n < 8; ++n) {
      f32x4 t = acc[n];
      t[0] *= af4[0]; t[1] *= af4[1]; t[2] *= af4[2]; t[3] *= af4[3];
      acc[n] = t;
    }

    // PV: redistribute P^T (held as kv=4g+r per subtile) into A-frag P[q=l&15][kv=8g+j]
#pragma unroll
    for (int c = 0; c < 2; ++c) {
      int srcA = ((2 * (g & 1)) << 4) | q15;
      int srcB = srcA + 16;
      u32 a00 = __shfl(pk[2 * c][0], srcA),     a01 = __shfl(pk[2 * c][1], srcA);
      u32 a02 = __shfl(pk[2 * c][0], srcB),     a03 = __shfl(pk[2 * c][1], srcB);
      u32 a10 = __shfl(pk[2 * c + 1][0], srcA), a11 = __shfl(pk[2 * c + 1][1], srcA);
      u32 a12 = __shfl(pk[2 * c + 1][0], srcB), a13 = __shfl(pk[2 * c + 1][1], srcB);
      bool hi = (g & 2) != 0;
      union { u32 u[4]; bf16x8 v; } afr;
      afr.u[0] = hi ? a10 : a00;
      afr.u[1] = hi ? a11 : a01;
      afr.u[2] = hi ? a12 : a02;
      afr.u[3] = hi ? a13 : a03;
#pragma unroll
      for (int n = 0; n < 8; ++n) {
        int d = n * 16 + q15;
        const char* vr = Vs + d * 128;
        int sw = (d & 7) << 4;
        bf16x8 bv = *(const bf16x8*)(vr + ((c * 64 + g * 16) ^ sw));
        acc[n] = __builtin_amdgcn_mfma_f32_16x16x32_bf16(afr.v, bv, acc[n], 0, 0, 0);
      }
    }
    __syncthreads();
  }

  // epilogue: divide by l, store bf16 to [b][s][h*128+d]
  float linv[4];
#pragma unroll
  for (int r = 0; r < 4; ++r) linv[r] = 1.0f / __shfl(lrun, g * 4 + r);
#pragma unroll
  for (int n = 0; n < 8; ++n)
#pragma unroll
    for (int r = 0; r < 4; ++r) {
      size_t orow = (size_t)b * S_LEN + qb + w * 16 + g * 4 + r;
      O[orow * DM + h * DH + n * 16 + q15] = f2bf(acc[n][r] * linv[r]);
    }
}

extern "C" void kernel_launch(void* const* d_in, const int* in_sizes, int n_in,
                              void* d_out, int out_size, void* d_ws, size_t ws_size,
                              hipStream_t stream) {
  (void)in_sizes; (void)n_in; (void)out_size; (void)ws_size;
  const float* x  = (const float*)d_in[0];
  const float* Wq = (const float*)d_in[1];
  const float* Wk = (const float*)d_in[2];
  const float* Wv = (const float*)d_in[3];
  const float* Wo = (const float*)d_in[4];
  const float* qw = (const float*)d_in[5];
  const float* kw = (const float*)d_in[6];

  char* ws = (char*)d_ws;
  // ws layout (~61 MB). attn_out aliases xb (xb dead after gemm1).
  u16*   xb    = (u16*)(ws + 0);                       // 16.8 MB [4096][2048]
  u16*   wqkvt = (u16*)(ws + 16777216);                // 12.6 MB [3072][2048]
  u16*   wot   = (u16*)(ws + 29360128);                //  8.4 MB [2048][2048]
  u16*   qo    = (u16*)(ws + 37748736);                // 16.8 MB [B][16][S][128]
  u16*   ko    = (u16*)(ws + 54525952);                //  4.2 MB [B][4][S][128]
  u16*   vt    = (u16*)(ws + 58720256);                //  4.2 MB [B][4][128][S]
  float* ctab  = (float*)(ws + 62914560);              //  0.5 MB
  float* stab  = (float*)(ws + 63438848);              //  0.5 MB
  u16*   qkvp  = (u16*)d_out;                          // 25.2 MB staged in d_out
  u16*   attn  = (u16*)(ws + 0);                       // aliases xb
  float* outp  = (float*)d_out;

  convert_x_kernel<<<4096, 256, 0, stream>>>(x, xb);
  transpose_w_kernel<<<dim3(32, 32), 256, 0, stream>>>(Wq, wqkvt, 2048);
  transpose_w_kernel<<<dim3(32, 8),  256, 0, stream>>>(Wk, wqkvt + (size_t)2048 * 2048, 512);
  transpose_w_kernel<<<dim3(32, 8),  256, 0, stream>>>(Wv, wqkvt + (size_t)2560 * 2048, 512);
  transpose_w_kernel<<<dim3(32, 32), 256, 0, stream>>>(Wo, wot, 2048);
  rope_tables_kernel<<<512, 256, 0, stream>>>(ctab, stab);

  gemm_bt<0><<<dim3(24, 32), 256, 0, stream>>>(xb, wqkvt, qkvp, MROWS, QKV_N, DM);
  norm_rope_kernel<<<20480, 256, 0, stream>>>(qkvp, qw, kw, ctab, stab, qo, ko);
  vtrans_kernel<<<dim3(32, 2, 8), 256, 0, stream>>>(qkvp, vt);
  attn_kernel<<<dim3(32, 32), 256, 0, stream>>>(qo, ko, vt, attn);
  gemm_bt<1><<<dim3(16, 32), 256, 0, stream>>>(attn, wot, outp, MROWS, DM, DM);
}

// Round 2
// 250.788 us; speedup vs baseline: 1.2671x; 1.2671x over previous
//
#include <hip/hip_runtime.h>
#include <stdint.h>

typedef __attribute__((ext_vector_type(8))) short bf16x8;
typedef __attribute__((ext_vector_type(4))) float f32x4;
typedef unsigned short u16;
typedef unsigned int   u32;

#define S_LEN 2048
#define NH    16
#define NKV   4
#define DH    128
#define DM    2048
#define QKV_N 3072
#define MROWS 4096   // B*S

__device__ __forceinline__ u16 f2bf(float x) {
  u32 u = __float_as_uint(x);
  return (u16)((u + 0x7fffu + ((u >> 16) & 1u)) >> 16);   // RNE
}
__device__ __forceinline__ float bf2f(u16 h) {
  return __uint_as_float(((u32)h) << 16);
}
__device__ __forceinline__ u32 packbf(float lo, float hi) {
  return (u32)f2bf(lo) | ((u32)f2bf(hi) << 16);
}
__device__ __forceinline__ void gload_lds16(const void* g, void* l) {
  __builtin_amdgcn_global_load_lds((const __attribute__((address_space(1))) void*)g,
                                   (__attribute__((address_space(3))) void*)l, 16, 0, 0);
}

// ---------------- f32 -> bf16 convert (vectorized, G13) ----------------
__global__ void __launch_bounds__(256) convert_x_kernel(const float* __restrict__ x,
                                                        u16* __restrict__ o) {
  int idx = (blockIdx.x * 256 + threadIdx.x) * 8;
  float4 a = *(const float4*)(x + idx);
  float4 b = *(const float4*)(x + idx + 4);
  union { u16 s[8]; uint4 v; } t;
  t.s[0] = f2bf(a.x); t.s[1] = f2bf(a.y); t.s[2] = f2bf(a.z); t.s[3] = f2bf(a.w);
  t.s[4] = f2bf(b.x); t.s[5] = f2bf(b.y); t.s[6] = f2bf(b.z); t.s[7] = f2bf(b.w);
  *(uint4*)(o + idx) = t.v;
}

// ------------- W [2048][N] f32  ->  Wt [N][2048] bf16 (LDS tiled) -------------
__global__ void __launch_bounds__(256) transpose_w_kernel(const float* __restrict__ src,
                                                          u16* __restrict__ dst, int N) {
  __shared__ float t[64][65];
  const int bx = blockIdx.x, by = blockIdx.y, tid = threadIdx.x;
#pragma unroll
  for (int rep = 0; rep < 16; ++rep) {
    int lin = rep * 256 + tid;
    int i = lin >> 6, jj = lin & 63;                 // i = k-local, jj = n-local
    t[i][jj] = src[(size_t)(bx * 64 + i) * N + by * 64 + jj];
  }
  __syncthreads();
#pragma unroll
  for (int rep = 0; rep < 16; ++rep) {
    int lin = rep * 256 + tid;
    int nr = lin >> 6, kc = lin & 63;
    dst[(size_t)(by * 64 + nr) * DM + bx * 64 + kc] = f2bf(t[kc][nr]);
  }
}

// ------------- RoPE tables: ctab/stab[s*64 + i] -------------
__global__ void __launch_bounds__(256) rope_tables_kernel(float* __restrict__ ct,
                                                          float* __restrict__ st_) {
  int idx = blockIdx.x * 256 + threadIdx.x;          // 2048*64
  int s = idx >> 6, i = idx & 63;
  const float L2_10000 = 13.287712379549449f;
  float freq = exp2f(-(float)i * (1.0f / 64.0f) * L2_10000);
  float ang = (float)s * freq;
  ct[idx] = cosf(ang);
  st_[idx] = sinf(ang);
}

// ------------- GEMM: C[M][N] = A[M][K](bf16) * Bt[N][K](bf16)^T  (m97 structure) -------------
template <int OUTF32>
__global__ void __launch_bounds__(256) gemm_bt(const u16* __restrict__ A,
                                               const u16* __restrict__ Bt,
                                               void* __restrict__ C,
                                               int M, int N, int K) {
  __shared__ __align__(16) u16 As[128 * 32];
  __shared__ __align__(16) u16 Bs[128 * 32];
  const int tid = threadIdx.x;
  const int w = tid >> 6, l = tid & 63;
  const int g = l >> 4, q15 = l & 15;
  const int row0 = blockIdx.y * 128, col0 = blockIdx.x * 128;
  const int wm = (w >> 1) * 64, wn = (w & 1) * 64;
  const f32x4 fz = {0.f, 0.f, 0.f, 0.f};
  f32x4 acc[4][4];
#pragma unroll
  for (int m = 0; m < 4; ++m)
#pragma unroll
    for (int n = 0; n < 4; ++n) acc[m][n] = fz;

  for (int kt = 0; kt < K; kt += 32) {
#pragma unroll
    for (int c = 0; c < 2; ++c) {
      int P = (w * 2 + c) * 1024;
      int Pl = P + l * 16;
      int arow = Pl >> 6, acolb = Pl & 63;          // 64B per 32-elem row
      gload_lds16((const char*)A + ((size_t)(row0 + arow) * K + kt) * 2 + acolb,
                  (char*)As + P);
      gload_lds16((const char*)Bt + ((size_t)(col0 + arow) * K + kt) * 2 + acolb,
                  (char*)Bs + P);
    }
    __syncthreads();
    bf16x8 af[4], bfv[4];
#pragma unroll
    for (int m = 0; m < 4; ++m)
      af[m] = *(const bf16x8*)((const char*)As + (wm + m * 16 + q15) * 64 + g * 16);
#pragma unroll
    for (int n = 0; n < 4; ++n)
      bfv[n] = *(const bf16x8*)((const char*)Bs + (wn + n * 16 + q15) * 64 + g * 16);
#pragma unroll
    for (int m = 0; m < 4; ++m)
#pragma unroll
      for (int n = 0; n < 4; ++n)
        acc[m][n] = __builtin_amdgcn_mfma_f32_16x16x32_bf16(af[m], bfv[n], acc[m][n], 0, 0, 0);
    __syncthreads();
  }
#pragma unroll
  for (int m = 0; m < 4; ++m)
#pragma unroll
    for (int n = 0; n < 4; ++n)
#pragma unroll
      for (int r = 0; r < 4; ++r) {
        int rr = row0 + wm + m * 16 + g * 4 + r;    // C/D: row=(l>>4)*4+reg
        int cc = col0 + wn + n * 16 + q15;          //      col=l&15
        float v = acc[m][n][r];
        if (OUTF32) ((float*)C)[(size_t)rr * N + cc] = v;
        else        ((u16*)C)[(size_t)rr * N + cc]  = f2bf(v);
      }
}

// ------------- fused RMSNorm + RoPE; one wave per (row, head-job) -------------
// jobs 0..15 = q heads (pre-scaled by 1/sqrt(DH)), 16..19 = k heads
__global__ void __launch_bounds__(256) norm_rope_kernel(const u16* __restrict__ qkv,
                                                        const float* __restrict__ qw,
                                                        const float* __restrict__ kw,
                                                        const float* __restrict__ ct,
                                                        const float* __restrict__ st_,
                                                        u16* __restrict__ Qo,
                                                        u16* __restrict__ Ko) {
  int wid = blockIdx.x * 4 + (threadIdx.x >> 6);
  int l = threadIdx.x & 63;
  int row = wid / 20;
  int j = wid - row * 20;
  int b = row >> 11, s = row & 2047;
  bool isq = j < 16;
  int h = isq ? j : (j - 16);
  const u16* src = qkv + (size_t)row * QKV_N + (isq ? h * DH : (2048 + h * DH));
  float x1 = bf2f(src[l]), x2 = bf2f(src[l + 64]);
  float ss = x1 * x1 + x2 * x2;
#pragma unroll
  for (int off = 32; off > 0; off >>= 1) ss += __shfl_xor(ss, off);
  float rn = rsqrtf(ss * (1.0f / 128.0f) + 1e-6f);
  const float* wv = isq ? qw : kw;
  float n1 = x1 * rn * wv[l], n2 = x2 * rn * wv[l + 64];
  float cv = ct[s * 64 + l], sv = st_[s * 64 + l];
  float o1 = n1 * cv - n2 * sv;
  float o2 = n2 * cv + n1 * sv;
  float scale = isq ? 0.08838834764831845f : 1.0f;   // 1/sqrt(128) folded into Q
  u16* dst = isq ? (Qo + ((size_t)(b * NH + h) * S_LEN + s) * DH)
                 : (Ko + ((size_t)(b * NKV + h) * S_LEN + s) * DH);
  dst[l]      = f2bf(o1 * scale);
  dst[l + 64] = f2bf(o2 * scale);
}

// ------------- V transpose: qkv[...,2560+h*128+d] -> vt[(b*4+h)*128+d][S] -------------
__global__ void __launch_bounds__(256) vtrans_kernel(const u16* __restrict__ qkv,
                                                     u16* __restrict__ vt) {
  __shared__ u16 t[64][65];
  const int st = blockIdx.x, dt = blockIdx.y, bz = blockIdx.z;  // bz = b*4+h
  const int tid = threadIdx.x;
#pragma unroll
  for (int rep = 0; rep < 16; ++rep) {
    int lin = rep * 256 + tid;
    int i = lin >> 6, jj = lin & 63;                // i = s-local, jj = d-local
    t[i][jj] = qkv[(size_t)((bz >> 2) * S_LEN + st * 64 + i) * QKV_N
                   + 2560 + (bz & 3) * DH + dt * 64 + jj];
  }
  __syncthreads();
#pragma unroll
  for (int rep = 0; rep < 16; ++rep) {
    int lin = rep * 256 + tid;
    int dr = lin >> 6, sc = lin & 63;
    vt[((size_t)bz * DH + dt * 64 + dr) * S_LEN + st * 64 + sc] = t[sc][dr];
  }
}

// ------------- flash attention: 64 q-rows/block, 4 waves (16 q each), KV tile 64 -------------
// Double-buffered K/V LDS tiles (T3 2-phase: stage(next) -> compute(cur) -> barrier),
// LPT block order (longest blocks dispatched first).
__global__ void __launch_bounds__(256) attn_kernel(const u16* __restrict__ Qg,
                                                   const u16* __restrict__ Kg,
                                                   const u16* __restrict__ Vt,
                                                   u16* __restrict__ O) {
  __shared__ __align__(16) char smem[65536];   // [2][ K:16KB | V:16KB ]
  const int tid = threadIdx.x;
  const int w = tid >> 6, l = tid & 63;
  const int g = l >> 4, q15 = l & 15;
  const int id = blockIdx.x;
  const int bx = 31 - (id >> 5);              // LPT: longest first
  const int bh = id & 31;                     // b*16 + h
  const int qb = bx * 64;
  const int b = bh >> 4, h = bh & 15;
  const int kvh = h >> 2;                     // GQA: 4 q-heads per kv-head
  const int nkt = bx;

  // Q rows in registers: lane holds query row (qb + w*16 + q15), k-chunk g*8 within 32-chunk c
  bf16x8 qreg[4];
  const u16* Qrow = Qg + ((size_t)(b * NH + h) * S_LEN + qb + w * 16 + q15) * DH;
#pragma unroll
  for (int c = 0; c < 4; ++c)
    qreg[c] = *(const bf16x8*)(Qrow + c * 32 + g * 8);

  const char* Kbase = (const char*)(Kg + (size_t)(b * NKV + kvh) * S_LEN * DH);
  const char* Vbase = (const char*)(Vt + (size_t)(b * NKV + kvh) * DH * S_LEN);

  // stage KV tile kt into buffer `buf` (K rows 256B, V rows 128B, XOR-swizzled source; rule 21)
  auto stage = [&](int buf, int kt) {
    const char* Kt  = Kbase + (size_t)kt * 64 * 256;
    const char* Vtb = Vbase + (size_t)kt * 128;
    char* Ksb = smem + buf * 32768;
    char* Vsb = Ksb + 16384;
#pragma unroll
    for (int i = 0; i < 4; ++i) {
      int P = i * 4096 + w * 1024;
      int Pl = P + l * 16;
      {
        int row = Pl >> 8; int cb = (Pl & 255) ^ ((row & 7) << 4);
        gload_lds16(Kt + (size_t)row * 256 + cb, Ksb + P);
      }
      {
        int row = Pl >> 7; int cb = (Pl & 127) ^ ((row & 7) << 4);
        gload_lds16(Vtb + (size_t)row * (S_LEN * 2) + cb, Vsb + P);
      }
    }
  };

  const f32x4 fz = {0.f, 0.f, 0.f, 0.f};
  f32x4 acc[8];
#pragma unroll
  for (int n = 0; n < 8; ++n) acc[n] = fz;
  float mrun = -1e30f, lrun = 0.f;

  stage(0, 0);
  __syncthreads();
  int cur = 0;

  for (int kt = 0; kt <= nkt; ++kt) {
    if (kt < nkt) stage(cur ^ 1, kt + 1);     // prefetch next tile (overlaps compute)
    const char* Ks = smem + cur * 32768;
    const char* Vs = Ks + 16384;

    // QK^T swapped: D = K * Q^T -> S^T[kv][q]; lane: q=l&15, kv=st*16+4g+r
    f32x4 sa[4];
#pragma unroll
    for (int stt = 0; stt < 4; ++stt) sa[stt] = fz;
#pragma unroll
    for (int stt = 0; stt < 4; ++stt) {
      int krow = stt * 16 + q15;
      const char* kr = Ks + krow * 256;
      int sw = (krow & 7) << 4;
#pragma unroll
      for (int c = 0; c < 4; ++c) {
        bf16x8 kf = *(const bf16x8*)(kr + ((c * 64 + g * 16) ^ sw));
        sa[stt] = __builtin_amdgcn_mfma_f32_16x16x32_bf16(kf, qreg[c], sa[stt], 0, 0, 0);
      }
    }

    // online softmax (scale pre-folded into Q)
    const bool domask = (kt == nkt);
    float sv[16];
    float tmax = -1e30f;
#pragma unroll
    for (int stt = 0; stt < 4; ++stt)
#pragma unroll
      for (int r = 0; r < 4; ++r) {
        float v = sa[stt][r];
        if (domask) {
          int kvg = kt * 64 + stt * 16 + g * 4 + r;
          int qg  = qb + w * 16 + q15;
          if (kvg > qg) v = -1e30f;
        }
        sv[stt * 4 + r] = v;
        tmax = fmaxf(tmax, v);
      }
    tmax = fmaxf(tmax, __shfl_xor(tmax, 16));
    tmax = fmaxf(tmax, __shfl_xor(tmax, 32));
    float mnew = fmaxf(mrun, tmax);
    float alpha = __expf(mrun - mnew);
    float tsum = 0.f;
    u32 pk[4][2];
#pragma unroll
    for (int stt = 0; stt < 4; ++stt) {
      float p0 = __expf(sv[stt * 4 + 0] - mnew);
      float p1 = __expf(sv[stt * 4 + 1] - mnew);
      float p2 = __expf(sv[stt * 4 + 2] - mnew);
      float p3 = __expf(sv[stt * 4 + 3] - mnew);
      tsum += p0 + p1 + p2 + p3;
      pk[stt][0] = packbf(p0, p1);
      pk[stt][1] = packbf(p2, p3);
    }
    tsum += __shfl_xor(tsum, 16);
    tsum += __shfl_xor(tsum, 32);
    lrun = lrun * alpha + tsum;
    mrun = mnew;

    // rescale acc rows (row q' = 4g+r needs alpha of lane q')
    float af4[4];
#pragma unroll
    for (int r = 0; r < 4; ++r) af4[r] = __shfl(alpha, g * 4 + r);
#pragma unroll
    for (int n = 0; n < 8; ++n) {
      f32x4 t = acc[n];
      t[0] *= af4[0]; t[1] *= af4[1]; t[2] *= af4[2]; t[3] *= af4[3];
      acc[n] = t;
    }

    // PV: redistribute P^T (held as kv=4g+r per subtile) into A-frag P[q=l&15][kv=8g+j]
#pragma unroll
    for (int c = 0; c < 2; ++c) {
      int srcA = ((2 * (g & 1)) << 4) | q15;
      int srcB = srcA + 16;
      u32 a00 = __shfl(pk[2 * c][0], srcA),     a01 = __shfl(pk[2 * c][1], srcA);
      u32 a02 = __shfl(pk[2 * c][0], srcB),     a03 = __shfl(pk[2 * c][1], srcB);
      u32 a10 = __shfl(pk[2 * c + 1][0], srcA), a11 = __shfl(pk[2 * c + 1][1], srcA);
      u32 a12 = __shfl(pk[2 * c + 1][0], srcB), a13 = __shfl(pk[2 * c + 1][1], srcB);
      bool hi = (g & 2) != 0;
      union { u32 u[4]; bf16x8 v; } afr;
      afr.u[0] = hi ? a10 : a00;
      afr.u[1] = hi ? a11 : a01;
      afr.u[2] = hi ? a12 : a02;
      afr.u[3] = hi ? a13 : a03;
#pragma unroll
      for (int n = 0; n < 8; ++n) {
        int d = n * 16 + q15;
        const char* vr = Vs + d * 128;
        int sw = (d & 7) << 4;
        bf16x8 bv = *(const bf16x8*)(vr + ((c * 64 + g * 16) ^ sw));
        acc[n] = __builtin_amdgcn_mfma_f32_16x16x32_bf16(afr.v, bv, acc[n], 0, 0, 0);
      }
    }
    __syncthreads();   // drains prefetch (vmcnt 0) + guards buffer reuse
    cur ^= 1;
  }

  // epilogue: divide by l, store bf16 to [b][s][h*128+d]
  float linv[4];
#pragma unroll
  for (int r = 0; r < 4; ++r) linv[r] = 1.0f / __shfl(lrun, g * 4 + r);
#pragma unroll
  for (int n = 0; n < 8; ++n)
#pragma unroll
    for (int r = 0; r < 4; ++r) {
      size_t orow = (size_t)b * S_LEN + qb + w * 16 + g * 4 + r;
      O[orow * DM + h * DH + n * 16 + q15] = f2bf(acc[n][r] * linv[r]);
    }
}

extern "C" void kernel_launch(void* const* d_in, const int* in_sizes, int n_in,
                              void* d_out, int out_size, void* d_ws, size_t ws_size,
                              hipStream_t stream) {
  (void)in_sizes; (void)n_in; (void)out_size; (void)ws_size;
  const float* x  = (const float*)d_in[0];
  const float* Wq = (const float*)d_in[1];
  const float* Wk = (const float*)d_in[2];
  const float* Wv = (const float*)d_in[3];
  const float* Wo = (const float*)d_in[4];
  const float* qw = (const float*)d_in[5];
  const float* kw = (const float*)d_in[6];

  char* ws = (char*)d_ws;
  // ws layout (~61 MB). attn_out aliases xb (xb dead after gemm1).
  u16*   xb    = (u16*)(ws + 0);                       // 16.8 MB [4096][2048]
  u16*   wqkvt = (u16*)(ws + 16777216);                // 12.6 MB [3072][2048]
  u16*   wot   = (u16*)(ws + 29360128);                //  8.4 MB [2048][2048]
  u16*   qo    = (u16*)(ws + 37748736);                // 16.8 MB [B][16][S][128]
  u16*   ko    = (u16*)(ws + 54525952);                //  4.2 MB [B][4][S][128]
  u16*   vt    = (u16*)(ws + 58720256);                //  4.2 MB [B][4][128][S]
  float* ctab  = (float*)(ws + 62914560);              //  0.5 MB
  float* stab  = (float*)(ws + 63438848);              //  0.5 MB
  u16*   qkvp  = (u16*)d_out;                          // 25.2 MB staged in d_out
  u16*   attn  = (u16*)(ws + 0);                       // aliases xb
  float* outp  = (float*)d_out;

  convert_x_kernel<<<4096, 256, 0, stream>>>(x, xb);
  transpose_w_kernel<<<dim3(32, 32), 256, 0, stream>>>(Wq, wqkvt, 2048);
  transpose_w_kernel<<<dim3(32, 8),  256, 0, stream>>>(Wk, wqkvt + (size_t)2048 * 2048, 512);
  transpose_w_kernel<<<dim3(32, 8),  256, 0, stream>>>(Wv, wqkvt + (size_t)2560 * 2048, 512);
  transpose_w_kernel<<<dim3(32, 32), 256, 0, stream>>>(Wo, wot, 2048);
  rope_tables_kernel<<<512, 256, 0, stream>>>(ctab, stab);

  gemm_bt<0><<<dim3(24, 32), 256, 0, stream>>>(xb, wqkvt, qkvp, MROWS, QKV_N, DM);
  norm_rope_kernel<<<20480, 256, 0, stream>>>(qkvp, qw, kw, ctab, stab, qo, ko);
  vtrans_kernel<<<dim3(32, 2, 8), 256, 0, stream>>>(qkvp, vt);
  attn_kernel<<<1024, 256, 0, stream>>>(qo, ko, vt, attn);
  gemm_bt<1><<<dim3(16, 32), 256, 0, stream>>>(attn, wot, outp, MROWS, DM, DM);
}